// Round 4
// baseline (669.487 us; speedup 1.0000x reference)
//
#include <hip/hip_runtime.h>

#define HH 384
#define WW 384
#define HWSZ (HH * WW)
#define NIMG 24

// packed {A,B}-pair coefficient table offsets (floats): 63 positions * NH * 2
#define PT0 0
#define PT1 252
#define PT2 756

typedef float v2f __attribute__((ext_vector_type(2)));

__device__ __forceinline__ int refl(int i, int n) {
    if (i < 0) i = -i;
    if (i >= n) i = 2 * n - 2 - i;
    return i;
}

// 5-tap Gaussian (sigma=1, normalized), double-precision constants cast to float
__device__ const float LPW[5] = {
    0.054488684549642945f, 0.24420134200323332f, 0.40261994689424746f,
    0.24420134200323332f, 0.054488684549642945f
};

// ---------------- filter generation (on device, fp64, matches numpy) -------
// Writes NORMALIZED fp64 filters to gtmp[28][225].
__global__ __launch_bounds__(256) void gen_filters(double* __restrict__ gtmp) {
    int f = blockIdx.x;  // 0..27
    int s, d, nd;
    if (f < 4)       { s = 0; nd = 4;  d = f;      }
    else if (f < 12) { s = 1; nd = 8;  d = f - 4;  }
    else             { s = 2; nd = 16; d = f - 12; }

    double angle = M_PI * (double)d / (double)nd;
    double scale = (double)(s + 1);
    double sx = 2.0 * scale, sy = 0.5 * scale;

    int tid = threadIdx.x;
    double val = 0.0;
    if (tid < 225) {
        int row = tid / 15, col = tid % 15;
        double X = (double)(col - 7);
        double Y = (double)(row - 7);
        double ca = cos(angle), sa = sin(angle);
        double Xr = X * ca - Y * sa;
        double Yr = X * sa + Y * ca;
        val = exp(-0.5 * (Xr * Xr / (sx * sx) + Yr * Yr / (sy * sy))) * Xr / (sx * sx);
    }

    __shared__ double red[256];
    red[tid] = val;
    __syncthreads();
    for (int st = 128; st > 0; st >>= 1) {
        if (tid < st) red[tid] += red[tid + st];
        __syncthreads();
    }
    double mean = red[0] / 225.0;
    __syncthreads();

    double dv = (tid < 225) ? (val - mean) : 0.0;
    red[tid] = dv * dv;
    __syncthreads();
    for (int st = 128; st > 0; st >>= 1) {
        if (tid < st) red[tid] += red[tid + st];
        __syncthreads();
    }
    double nrm = sqrt(red[0]);
    double inv = (nrm > 1e-6) ? (1.0 / nrm) : 1.0;

    if (tid < 225) {
        gtmp[(long)f * 225 + tid] = (val - mean) * inv;
    }
}

// ---------------- pack {P,Q} pair coefficient tables (fp64 combine) --------
// point-antisymmetry G(-u,-v) = -G(u,v); x-mirror G_{nd-d}(u,v) = G_d(u,-v).
// Per pair (d, nd-d): out_d = P + Q, out_{nd-d} = P - Q with
//   P-lane coef A = (G(u,v)+G(u,-v))/2, Q-lane coef B = (G(u,v)-G(u,-v))/2.
// 63 unified half-window positions j:
//   j=0..6   (0,v) v=1..7  : A == 0 exactly, B = G(0,v)
//   j=7..13  (u,0) u=1..7  : A = G(u,0),   B == 0 exactly
//   j=14..62 (u,v) u,v=1..7: generic {A,B}, data is {S,D}
// k=0 lanes come from different filters: P <- d=nh (x-sym), Q <- d=0 (x-antisym).
__global__ __launch_bounds__(256) void pack_tables(
    const double* __restrict__ gtmp, float* __restrict__ tab) {
    int s = blockIdx.x;  // 0..2
    int nh = (s == 0) ? 2 : (s == 1) ? 4 : 8;
    int fbase = (s == 0) ? 0 : (s == 1) ? 4 : 12;
    int off = (s == 0) ? PT0 : (s == 1) ? PT1 : PT2;

    for (int t = threadIdx.x; t < 63 * nh; t += 256) {
        int j = t / nh, k = t % nh;
        int u, v;
        if (j < 7)       { u = 0;     v = j + 1; }
        else if (j < 14) { u = j - 6; v = 0;     }
        else { int p = j - 14; u = p / 7 + 1; v = p % 7 + 1; }
        int dP = (k == 0) ? nh : k;
        int dQ = (k == 0) ? 0 : k;
        const double* FP = gtmp + (long)(fbase + dP) * 225;
        const double* FQ = gtmp + (long)(fbase + dQ) * 225;
        double A = 0.5 * (FP[(7 + u) * 15 + (7 + v)] + FP[(7 + u) * 15 + (7 - v)]);
        double B = 0.5 * (FQ[(7 + u) * 15 + (7 + v)] - FQ[(7 + u) * 15 + (7 - v)]);
        tab[off + 2 * (j * nh + k)]     = (float)A;
        tab[off + 2 * (j * nh + k) + 1] = (float)B;
    }
}

// ---------------- 5x5 separable Gaussian lowpass, reflect pad --------------
__global__ __launch_bounds__(256) void lp_kernel(
    const float* __restrict__ in, float* __restrict__ out, long ostride) {
    int n = blockIdx.z;
    int x = blockIdx.x * 32 + threadIdx.x;
    int y = blockIdx.y * 8 + threadIdx.y;
    const float* ip = in + (long)n * HWSZ;

    float acc = 0.f;
#pragma unroll
    for (int fy = 0; fy < 5; ++fy) {
        int yy = refl(y + fy - 2, HH);
        const float* rp = ip + yy * WW;
        float rs = 0.f;
#pragma unroll
        for (int fx = 0; fx < 5; ++fx) {
            int xx = refl(x + fx - 2, WW);
            rs = fmaf(LPW[fx], rp[xx], rs);
        }
        acc = fmaf(LPW[fy], rs, acc);
    }
    out[(long)n * ostride + y * WW + x] = acc;
}

// ---------------- directional 15x15 bank, reflect pad ----------------------
// band = A[n] - B[n] computed on the fly. NH = nd/2 pairs, R = rows/thread.
// Packed {P,Q} accumulators -> v_pk_fma_f32 (one inst = both streams).
// u-loop NOT unrolled (VGPR control; round-2 lesson: 188 VGPR -> 11% occ).
template <int NH, int R>
__global__ __launch_bounds__(256, 4) void dir_kernel(
    const float* __restrict__ A, long as,
    const float* __restrict__ B, long bs,
    const float* __restrict__ ptab,
    float* __restrict__ out, int c0) {
    constexpr int TH = 8 * R;            // tile height
    __shared__ float sm[TH + 14][48];

    int n = blockIdx.z;
    int tx = threadIdx.x, ty = threadIdx.y;
    int bx = blockIdx.x * 32, by = blockIdx.y * TH;

    const float* Ab = A + (long)n * as;
    const float* Bb = B + (long)n * bs;

    int lid = ty * 32 + tx;
    for (int l = lid; l < (TH + 14) * 46; l += 256) {
        int ly = l / 46, lx = l % 46;
        int gy = refl(by + ly - 7, HH);
        int gx = refl(bx + lx - 7, WW);
        long gi = (long)gy * WW + gx;
        sm[ly][lx] = Ab[gi] - Bb[gi];
    }
    __syncthreads();

    v2f acc[NH][R];  // .x = P, .y = Q
#pragma unroll
    for (int k = 0; k < NH; ++k)
#pragma unroll
        for (int r = 0; r < R; ++r) acc[k][r] = (v2f){0.f, 0.f};

    const v2f* pt = (const v2f*)ptab;

    // H0: u=0, v=1..7 (j = v-1): coef {0, B}, data {dv, dv}
#pragma unroll
    for (int v = 1; v <= 7; ++v) {
        v2f dv2[R];
#pragma unroll
        for (int r = 0; r < R; ++r) {
            const float* rp = &sm[ty + 7 + 8 * r][tx];  // col base = xc-7
            float dv = rp[7 + v] - rp[7 - v];
            dv2[r] = (v2f){dv, dv};
        }
        const v2f* cp = pt + (v - 1) * NH;
#pragma unroll
        for (int k = 0; k < NH; ++k) {
            v2f c = cp[k];
#pragma unroll
            for (int r = 0; r < R; ++r)
                acc[k][r] = __builtin_elementwise_fma(c, dv2[r], acc[k][r]);
        }
    }

    // u = 1..7 (runtime loop): Hc (j=6+u, coef {A,0}) + Hp (j=14+.., coef {A,B})
#pragma unroll 1
    for (int u = 1; u <= 7; ++u) {
        {
            v2f dc2[R];
#pragma unroll
            for (int r = 0; r < R; ++r) {
                int yb = ty + 7 + 8 * r;
                float t = sm[yb + u][tx + 7] - sm[yb - u][tx + 7];
                dc2[r] = (v2f){t, t};
            }
            const v2f* cp = pt + (6 + u) * NH;
#pragma unroll
            for (int k = 0; k < NH; ++k) {
                v2f c = cp[k];
#pragma unroll
                for (int r = 0; r < R; ++r)
                    acc[k][r] = __builtin_elementwise_fma(c, dc2[r], acc[k][r]);
            }
        }
#pragma unroll
        for (int v = 1; v <= 7; ++v) {
            v2f sd[R];
#pragma unroll
            for (int r = 0; r < R; ++r) {
                int yb = ty + 7 + 8 * r;
                const float* rpP = &sm[yb + u][tx];  // both reads same base -> ds_read2
                const float* rpM = &sm[yb - u][tx];
                v2f ab = (v2f){rpP[7 + v], rpP[7 - v]};   // {a, b}
                v2f dc = (v2f){rpM[7 - v], rpM[7 + v]};   // {d, c}
                v2f t = ab - dc;                           // packed: {t1, t2}
                sd[r] = (v2f){t.x + t.y, t.x - t.y};       // {S, D}
            }
            const v2f* cp = pt + (14 + (u - 1) * 7 + (v - 1)) * NH;
#pragma unroll
            for (int k = 0; k < NH; ++k) {
                v2f c = cp[k];
#pragma unroll
                for (int r = 0; r < R; ++r)
                    acc[k][r] = __builtin_elementwise_fma(c, sd[r], acc[k][r]);
            }
        }
    }

    // outputs: d=0 -> Q[0]; d=NH -> P[0]; pair k: d=k -> P+Q, d=2NH-k -> P-Q
    long ob = ((long)n * 29 + c0) * HWSZ;
#pragma unroll
    for (int r = 0; r < R; ++r) {
        long idx = ob + (long)(by + ty + r * 8) * WW + bx + tx;
        out[idx] = acc[0][r].y;
        out[idx + (long)NH * HWSZ] = acc[0][r].x;
#pragma unroll
        for (int k = 1; k < NH; ++k) {
            out[idx + (long)k * HWSZ] = acc[k][r].x + acc[k][r].y;
            out[idx + (long)(2 * NH - k) * HWSZ] = acc[k][r].x - acc[k][r].y;
        }
    }
}

extern "C" void kernel_launch(void* const* d_in, const int* in_sizes, int n_in,
                              void* d_out, int out_size, void* d_ws, size_t ws_size,
                              hipStream_t stream) {
    const float* x = (const float*)d_in[0];
    float* out = (float*)d_out;
    float* ws = (float*)d_ws;

    float* tab = ws;                        // 1764 floats of packed pair tables
    float* lp0 = ws + 2048;                 // 24 * HWSZ
    float* lp1 = lp0 + (long)NIMG * HWSZ;   // 24 * HWSZ
    // fp64 scratch for raw filters; overlaps lp0 (dead before lp0 is written,
    // stream-ordered). 6300 doubles = 12600 floats << NIMG*HWSZ.
    double* gtmp = (double*)lp0;

    gen_filters<<<28, 256, 0, stream>>>(gtmp);
    pack_tables<<<3, 256, 0, stream>>>(gtmp, tab);

    dim3 blk(32, 8);
    dim3 lpgrid(12, 48, NIMG);
    // lp0 = LP(x); lp1 = LP(lp0); lp2 = LP(lp1) -> out channel 28
    lp_kernel<<<lpgrid, blk, 0, stream>>>(x, lp0, HWSZ);
    lp_kernel<<<lpgrid, blk, 0, stream>>>(lp0, lp1, HWSZ);
    lp_kernel<<<lpgrid, blk, 0, stream>>>(lp1, out + 28l * HWSZ, 29l * HWSZ);

    // band0 = x - lp0      -> channels 0..3   (NH=2, R=4: 32x32 tiles)
    dir_kernel<2, 4><<<dim3(12, 12, NIMG), blk, 0, stream>>>(
        x, HWSZ, lp0, HWSZ, tab + PT0, out, 0);
    // band1 = lp0 - lp1    -> channels 4..11  (NH=4, R=4: 32x32 tiles)
    dir_kernel<4, 4><<<dim3(12, 12, NIMG), blk, 0, stream>>>(
        lp0, HWSZ, lp1, HWSZ, tab + PT1, out, 4);
    // band2 = lp1 - lp2    -> channels 12..27 (NH=8, R=2: 32x16 tiles)
    dir_kernel<8, 2><<<dim3(12, 24, NIMG), blk, 0, stream>>>(
        lp1, HWSZ, out + 28l * HWSZ, 29l * HWSZ, tab + PT2, out, 12);
}